// Round 2
// baseline (1329.441 us; speedup 1.0000x reference)
//
#include <hip/hip_runtime.h>

#define BATCH 8
#define NTOK 1315
#define DIM 512
#define HEADS 8
#define DH 64
#define NIMG 291
#define NGENE 1024
#define NQKV 1536
#define MROWS (BATCH * NTOK)
#define QSCALE 0.125f
#define KERN 33
#define KPAD 16
#define LDK 68   // padded LDS row stride (floats): 68%32=4 -> conflict-free

typedef float4 f4;

// ---------------- kernel 1: QKV GEMM ----------------
// qkv[m, c] = sum_k x[m,k] * w[k,c]; scatter to q/k/v in [b][h][n][dh] (q scaled)
__global__ __launch_bounds__(256) void qkv_gemm(
    const float* __restrict__ x, const float* __restrict__ w,
    float* __restrict__ qb, float* __restrict__ kb, float* __restrict__ vb)
{
    __shared__ float As[16][132];  // [k][m] transposed, padded
    __shared__ float Bs[16][132];  // [k][n], padded
    const int tid = threadIdx.x;
    const int m0 = blockIdx.x * 128;
    const int n0 = blockIdx.y * 128;
    const int tx = tid & 15;
    const int ty = tid >> 4;

    float acc[8][8];
#pragma unroll
    for (int i = 0; i < 8; ++i)
#pragma unroll
        for (int j = 0; j < 8; ++j) acc[i][j] = 0.f;

    const int ar = tid >> 2;
    const int ak = (tid & 3) << 2;
    const int bk = tid >> 4;
    const int bc = (tid & 15) << 3;

    for (int k0 = 0; k0 < DIM; k0 += 16) {
        __syncthreads();
#pragma unroll
        for (int rr = 0; rr < 2; ++rr) {
            int row = m0 + ar + rr * 64;
            f4 a = make_float4(0.f, 0.f, 0.f, 0.f);
            if (row < MROWS) a = *(const f4*)&x[(size_t)row * DIM + k0 + ak];
            As[ak + 0][ar + rr * 64] = a.x;
            As[ak + 1][ar + rr * 64] = a.y;
            As[ak + 2][ar + rr * 64] = a.z;
            As[ak + 3][ar + rr * 64] = a.w;
        }
        {
            const float* src = &w[(size_t)(k0 + bk) * NQKV + n0 + bc];
            *(f4*)&Bs[bk][bc]     = *(const f4*)src;
            *(f4*)&Bs[bk][bc + 4] = *(const f4*)(src + 4);
        }
        __syncthreads();
#pragma unroll
        for (int kk = 0; kk < 16; ++kk) {
            f4 a0 = *(f4*)&As[kk][ty * 8];
            f4 a1 = *(f4*)&As[kk][ty * 8 + 4];
            f4 b0 = *(f4*)&Bs[kk][tx * 8];
            f4 b1 = *(f4*)&Bs[kk][tx * 8 + 4];
            float av[8] = {a0.x, a0.y, a0.z, a0.w, a1.x, a1.y, a1.z, a1.w};
            float bv[8] = {b0.x, b0.y, b0.z, b0.w, b1.x, b1.y, b1.z, b1.w};
#pragma unroll
            for (int i = 0; i < 8; ++i)
#pragma unroll
                for (int j = 0; j < 8; ++j)
                    acc[i][j] = fmaf(av[i], bv[j], acc[i][j]);
        }
    }

    const int cbase = n0 + tx * 8;      // 8 consecutive cols, same which/head
    const int which = cbase >> 9;
    const int hh = (cbase >> 6) & 7;
    const int dh = cbase & 63;
    float* dst0 = (which == 0) ? qb : ((which == 1) ? kb : vb);
    const float sc = (which == 0) ? QSCALE : 1.0f;
#pragma unroll
    for (int i = 0; i < 8; ++i) {
        int m = m0 + ty * 8 + i;
        if (m < MROWS) {
            int b = m / NTOK;
            int n = m - b * NTOK;
            float* dst = dst0 + ((size_t)(b * HEADS + hh) * NTOK + n) * DH + dh;
            f4 r0 = make_float4(acc[i][0] * sc, acc[i][1] * sc, acc[i][2] * sc, acc[i][3] * sc);
            f4 r1 = make_float4(acc[i][4] * sc, acc[i][5] * sc, acc[i][6] * sc, acc[i][7] * sc);
            *(f4*)dst = r0;
            *(f4*)(dst + 4) = r1;
        }
    }
}

// Column j (0..1314) -> key token; v uses natural token j.
__device__ __forceinline__ int keymap(int j) {
    return (j < NGENE) ? (j + NIMG) : (j - NGENE);
}

// Stage one 64-row tile of K (remapped) and optionally V (natural) into LDS.
// Each wave-instruction covers 4 contiguous rows x 16 f4 -> fully coalesced
// global loads; LDS writes hit each bank exactly 8x (conflict-free minimum).
// Rows beyond NTOK are zero-filled (no NaN garbage downstream).
__device__ __forceinline__ void stage_tile(
    float (*Kl)[LDK], float (*Vl)[LDK],
    const float* __restrict__ kb, const float* __restrict__ vb,
    size_t base, int t0, int tid, bool withV)
{
#pragma unroll
    for (int u = 0; u < 4; ++u) {
        int idx = (u << 8) + tid;          // 0..1023
        int r = idx >> 4;
        int cf = (idx & 15) << 2;
        int j = t0 + r;
        f4 kv = make_float4(0.f, 0.f, 0.f, 0.f);
        f4 vv = kv;
        if (j < NTOK) {
            kv = *(const f4*)&kb[base + (size_t)keymap(j) * DH + cf];
            if (withV) vv = *(const f4*)&vb[base + (size_t)j * DH + cf];
        }
        *(f4*)&Kl[r][cf] = kv;
        if (withV) *(f4*)&Vl[r][cf] = vv;
    }
}

// Compute 16 column logits (this lane's 32-dim partial + pair reduce).
// 4 parallel FMA chains per column, 16 independent columns -> high ILP.
// Entries cc >= ncc are masked to -1e30 (post-shuffle).
__device__ __forceinline__ void logits16(
    const float (*Kl)[LDK], const f4* qr, int dlo, int c0, int ncc, float* lg)
{
#pragma unroll
    for (int cc = 0; cc < 16; ++cc) {
        f4 part = make_float4(0.f, 0.f, 0.f, 0.f);
#pragma unroll
        for (int j = 0; j < 8; ++j) {
            f4 kv = *(const f4*)&Kl[c0 + cc][dlo + j * 4];
            part.x = fmaf(qr[j].x, kv.x, part.x);
            part.y = fmaf(qr[j].y, kv.y, part.y);
            part.z = fmaf(qr[j].z, kv.z, part.z);
            part.w = fmaf(qr[j].w, kv.w, part.w);
        }
        float l = (part.x + part.y) + (part.z + part.w);
        l += __shfl_xor(l, 1, 64);      // full 64-dim logit on both lanes
        lg[cc] = (cc < ncc) ? l : -1e30f;
    }
}

// ---------------- kernel 2: fused attention (gene + image queries) ----------------
// grid.x = b*8+h ; grid.y 0..7 -> gene query chunks, 8..10 -> image query chunks.
// 2 threads per query (32 dims each). 128 queries per block.
__global__ __launch_bounds__(256) void attn_fused(
    const float* __restrict__ qb, const float* __restrict__ kb,
    const float* __restrict__ vb, float* __restrict__ out)
{
    __shared__ float Kl[64][LDK];
    __shared__ float Vl[64][LDK];
    const int tid = threadIdx.x;
    const int bh = blockIdx.x;                  // b*8+h
    const int b = bh >> 3, h = bh & 7;
    const size_t base = (size_t)bh * NTOK * DH;
    const int dlo = (tid & 1) * 32;
    const bool isGene = (blockIdx.y < 8);
    const int qi = (isGene ? blockIdx.y : (blockIdx.y - 8)) * 128 + (tid >> 1);
    const bool valid = isGene ? true : (qi < NIMG);
    const int qtok = isGene ? (NIMG + qi) : (valid ? qi : 0);

    f4 qr[8];
    {
        const float* qp = qb + base + (size_t)qtok * DH + dlo;
#pragma unroll
        for (int j = 0; j < 8; ++j) qr[j] = *(const f4*)&qp[j * 4];
    }

    f4 o[8];
#pragma unroll
    for (int j = 0; j < 8; ++j) o[j] = make_float4(0.f, 0.f, 0.f, 0.f);

    float lg[16];

    if (isGene) {
        // ---- plain online softmax over all 1315 remapped columns ----
        float m = -1e30f, s = 0.f;
        for (int t0 = 0; t0 < NTOK; t0 += 64) {
            __syncthreads();
            stage_tile(Kl, Vl, kb, vb, base, t0, tid, true);
            __syncthreads();
            int nc = NTOK - t0; if (nc > 64) nc = 64;
            for (int c0 = 0; c0 < nc; c0 += 16) {
                int ncc = nc - c0; if (ncc > 16) ncc = 16;
                logits16(Kl, qr, dlo, c0, ncc, lg);
                float tm = lg[0];
#pragma unroll
                for (int cc = 1; cc < 16; ++cc) tm = fmaxf(tm, lg[cc]);
                if (tm > m) {
                    float corr = __expf(m - tm);
                    s *= corr;
#pragma unroll
                    for (int j = 0; j < 8; ++j) {
                        o[j].x *= corr; o[j].y *= corr; o[j].z *= corr; o[j].w *= corr;
                    }
                    m = tm;
                }
#pragma unroll
                for (int cc = 0; cc < 16; ++cc) {
                    float p = __expf(lg[cc] - m);
                    s += p;
#pragma unroll
                    for (int j = 0; j < 8; ++j) {
                        f4 vv = *(const f4*)&Vl[c0 + cc][dlo + j * 4];
                        o[j].x = fmaf(p, vv.x, o[j].x); o[j].y = fmaf(p, vv.y, o[j].y);
                        o[j].z = fmaf(p, vv.z, o[j].z); o[j].w = fmaf(p, vv.w, o[j].w);
                    }
                }
            }
        }
        const float inv = 1.0f / s;
        float* op = out + ((size_t)(b * NTOK) + qi) * DIM + h * DH + dlo;
#pragma unroll
        for (int j = 0; j < 8; ++j) {
            f4 r = make_float4(o[j].x * inv, o[j].y * inv, o[j].z * inv, o[j].w * inv);
            *(f4*)&op[j * 4] = r;
        }
    } else {
        // ---- image queries: two-stage softmax ----
        // stage 1: softmax over gene cols (m1,s1); its max value is 1/s1.
        // stage 2: softmax over [softmaxed gene (1024), raw img logits (291)].
        float m1 = -1e30f, s1 = 0.f, m2 = -1e30f;
        for (int t0 = 0; t0 < NTOK; t0 += 64) {
            __syncthreads();
            stage_tile(Kl, Vl, kb, vb, base, t0, tid, false);
            __syncthreads();
            int nc = NTOK - t0; if (nc > 64) nc = 64;
            const bool geneTile = (t0 < NGENE);   // NGENE is a multiple of 64
            for (int c0 = 0; c0 < nc; c0 += 16) {
                int ncc = nc - c0; if (ncc > 16) ncc = 16;
                logits16(Kl, qr, dlo, c0, ncc, lg);
                float tm = lg[0];
#pragma unroll
                for (int cc = 1; cc < 16; ++cc) tm = fmaxf(tm, lg[cc]);
                if (geneTile) {
                    if (tm > m1) { s1 *= __expf(m1 - tm); m1 = tm; }
#pragma unroll
                    for (int cc = 0; cc < 16; ++cc) s1 += __expf(lg[cc] - m1);
                } else {
                    m2 = fmaxf(m2, tm);
                }
            }
        }
        const float inv_s1 = 1.0f / s1;
        const float M = fmaxf(inv_s1, m2);
        float Z = 0.f;
        for (int t0 = 0; t0 < NTOK; t0 += 64) {
            __syncthreads();
            stage_tile(Kl, Vl, kb, vb, base, t0, tid, true);
            __syncthreads();
            int nc = NTOK - t0; if (nc > 64) nc = 64;
            const bool geneTile = (t0 < NGENE);
            for (int c0 = 0; c0 < nc; c0 += 16) {
                int ncc = nc - c0; if (ncc > 16) ncc = 16;
                logits16(Kl, qr, dlo, c0, ncc, lg);
#pragma unroll
                for (int cc = 0; cc < 16; ++cc) {
                    float val = geneTile ? (__expf(lg[cc] - m1) * inv_s1) : lg[cc];
                    float wgt = __expf(val - M);
                    Z += wgt;
#pragma unroll
                    for (int j = 0; j < 8; ++j) {
                        f4 vv = *(const f4*)&Vl[c0 + cc][dlo + j * 4];
                        o[j].x = fmaf(wgt, vv.x, o[j].x); o[j].y = fmaf(wgt, vv.y, o[j].y);
                        o[j].z = fmaf(wgt, vv.z, o[j].z); o[j].w = fmaf(wgt, vv.w, o[j].w);
                    }
                }
            }
        }
        if (valid) {
            const float inv = 1.0f / Z;
            float* op = out + ((size_t)(b * NTOK) + NGENE + qi) * DIM + h * DH + dlo;
#pragma unroll
            for (int j = 0; j < 8; ++j) {
                f4 r = make_float4(o[j].x * inv, o[j].y * inv, o[j].z * inv, o[j].w * inv);
                *(f4*)&op[j * 4] = r;
            }
        }
    }
}

// ---------------- kernel 3: depthwise conv33 over tokens, added to out ----------------
// res[b,h,i,dd] = sum_t v[b,h,i+t-16,dd]*w[h,t]; added to out row i (concat order row i)
__global__ __launch_bounds__(256) void conv_add(
    const float* __restrict__ vb, const float* __restrict__ wres,
    float* __restrict__ out)
{
    __shared__ float Vs[128 + 32][DH + 4];
    __shared__ float wl[KERN];
    const int tid = threadIdx.x;
    const int bh = blockIdx.x;
    const int r0 = blockIdx.y * 128;
    const int b = bh >> 3, h = bh & 7;
    const size_t base = (size_t)bh * NTOK * DH;

    if (tid < KERN) wl[tid] = wres[h * KERN + tid];
    {
        int col = (tid & 15) << 2;
        for (int i = tid >> 4; i < 128 + 32; i += 16) {
            int row = r0 - KPAD + i;
            f4 val = make_float4(0.f, 0.f, 0.f, 0.f);
            if (row >= 0 && row < NTOK)
                val = *(const f4*)&vb[base + (size_t)row * DH + col];
            *(f4*)&Vs[i][col] = val;
        }
    }
    __syncthreads();

    const int row = tid >> 1;            // 0..127
    const int dlo = (tid & 1) * 32;
    const int grow = r0 + row;
    if (grow < NTOK) {
        f4 acc[8];
#pragma unroll
        for (int j = 0; j < 8; ++j) acc[j] = make_float4(0.f, 0.f, 0.f, 0.f);
#pragma unroll
        for (int t = 0; t < KERN; ++t) {
            float wgt = wl[t];
#pragma unroll
            for (int j = 0; j < 8; ++j) {
                f4 vv = *(const f4*)&Vs[row + t][dlo + j * 4];
                acc[j].x = fmaf(wgt, vv.x, acc[j].x); acc[j].y = fmaf(wgt, vv.y, acc[j].y);
                acc[j].z = fmaf(wgt, vv.z, acc[j].z); acc[j].w = fmaf(wgt, vv.w, acc[j].w);
            }
        }
        float* op = out + ((size_t)(b * NTOK) + grow) * DIM + h * DH + dlo;
#pragma unroll
        for (int j = 0; j < 8; ++j) {
            f4 cur = *(f4*)&op[j * 4];
            cur.x += acc[j].x; cur.y += acc[j].y; cur.z += acc[j].z; cur.w += acc[j].w;
            *(f4*)&op[j * 4] = cur;
        }
    }
}

extern "C" void kernel_launch(void* const* d_in, const int* in_sizes, int n_in,
                              void* d_out, int out_size, void* d_ws, size_t ws_size,
                              hipStream_t stream)
{
    const float* x     = (const float*)d_in[0];
    const float* w_qkv = (const float*)d_in[1];
    const float* w_res = (const float*)d_in[2];
    float* out = (float*)d_out;

    const size_t per = (size_t)BATCH * HEADS * NTOK * DH;  // 5,386,240 floats
    float* qb = (float*)d_ws;
    float* kb = qb + per;
    float* vb = kb + per;

    {
        dim3 g((MROWS + 127) / 128, NQKV / 128);   // 83 x 12
        qkv_gemm<<<g, 256, 0, stream>>>(x, w_qkv, qb, kb, vb);
    }
    {
        dim3 g(BATCH * HEADS, 8 + 3);              // 64 x 11 (gene chunks + image chunks)
        attn_fused<<<g, 256, 0, stream>>>(qb, kb, vb, out);
    }
    {
        dim3 g(BATCH * HEADS, (NTOK + 127) / 128); // 64 x 11
        conv_add<<<g, 256, 0, stream>>>(vb, w_res, out);
    }
}

// Round 7
// 262.794 us; speedup vs baseline: 5.0589x; 5.0589x over previous
//
#include <hip/hip_runtime.h>

#define BATCH 8
#define NTOK 1315
#define DIM 512
#define HEADS 8
#define DH 64
#define NIMG 291
#define NGENE 1024
#define NQKV 1536
#define QSCALE 0.125f
#define KERN 33
#define NT 21            // 21 tiles of 64 keys (1315 -> 1344, tail masked)
#define KROWS 1344       // kbb rows per bh (padded to tile multiple)
#define VROW 1392        // vtb row width: 16 left pad + 1315 + 61 right pad (zeroed)
#define VPAD 16
#define PLD 72           // Pl row stride in shorts: 144B rows -> short8 reads 16B-aligned for ALL lanes

typedef float4 f4;
typedef __attribute__((ext_vector_type(8)))  short  short8;   // 8 bf16 = 4 VGPR (MFMA A/B frag)
typedef __attribute__((ext_vector_type(16))) float  fv16;     // MFMA C/D for 32x32
#define MFMA __builtin_amdgcn_mfma_f32_32x32x16_bf16

__device__ __forceinline__ ushort f2bf(float f) {   // RNE float->bf16 bits
    union { float f; uint u; } v; v.f = f;
    uint u = v.u;
    uint r = u + 0x7FFFu + ((u >> 16) & 1u);
    return (ushort)(r >> 16);
}
__device__ __forceinline__ uint pack2(float a, float b) {
    return (uint)f2bf(a) | ((uint)f2bf(b) << 16);
}

// ---------------- kernel 0: prep ----------------
// (a) zero kbb tail rows + vtb pad columns (results independent of 0xAA ws poison)
// (b) build wtb bf16 [n][k] = transpose-convert of w_qkv [k][n]
__global__ __launch_bounds__(256) void prep(
    const float* __restrict__ w,
    ushort* __restrict__ kbb, ushort* __restrict__ vtb, ushort* __restrict__ wtb)
{
    const int step = gridDim.x * 256;
    const int tid0 = blockIdx.x * 256 + threadIdx.x;

    const int ktail = 64 * (KROWS - NTOK) * DH;          // 118,784
    for (int i = tid0; i < ktail; i += step) {
        int bh = i / ((KROWS - NTOK) * DH);
        int r  = i % ((KROWS - NTOK) * DH);
        kbb[(size_t)bh * KROWS * DH + (size_t)(NTOK + r / DH) * DH + (r % DH)] = 0;
    }
    const int vpadw = VPAD + (VROW - VPAD - NTOK);       // 16 + 61 = 77
    const int vtot = 64 * DH * vpadw;                    // 315,392
    for (int i = tid0; i < vtot; i += step) {
        int row = i / vpadw, c = i % vpadw;
        int col = (c < VPAD) ? c : (VPAD + NTOK + (c - VPAD));
        vtb[(size_t)row * VROW + col] = 0;
    }
    // wtb[n*DIM + k] = bf16(w[k*NQKV + n]); reads coalesced over n
    const int wtot = NQKV * DIM;                         // 786,432
    for (int i = tid0; i < wtot; i += step) {
        int k = i / NQKV, n = i - k * NQKV;
        wtb[(size_t)n * DIM + k] = f2bf(w[(size_t)k * NQKV + n]);
    }
}

// ---------------- kernel 1: QKV GEMM (bf16 MFMA core, scatter epilogue) ----------
// grid (8*11, 12). C = x(1315x512 per batch) @ w(512x1536). 128x128 tile, BK=64,
// 4 waves 2x2, each wave 64x64 out = 4 mfma_32x32x16 accumulators. Single LDS
// buffer, sync-stage-sync-compute (race-free by construction). XOR-swizzled LDS.
// Staging: 128 rows x 64 cols = 1024 uint4 -> 4 per thread (u < 4).
// q -> qbb bf16 [bh][tok][64] (scaled); k -> kbb [bh][concat_col][64] (remapped);
// v -> vtb [bh][d][VROW] transposed, VPAD left pad.
__global__ __launch_bounds__(256) void qkv_gemm(
    const float* __restrict__ x, const ushort* __restrict__ wtb,
    ushort* __restrict__ qbb, ushort* __restrict__ kbb, ushort* __restrict__ vtb)
{
    __shared__ short As[128 * 64];   // [m-row][64 k] swizzled, 16 KB
    __shared__ short Bsh[128 * 64];  // [n-col][64 k] swizzled, 16 KB

    const int tid = threadIdx.x;
    const int lane = tid & 63;
    const int wv = tid >> 6;
    const int half = lane >> 5;
    const int ql = lane & 31;
    const int wy = wv >> 1, wx = wv & 1;       // 2x2 wave grid
    const int b  = blockIdx.x / 11;
    const int m0 = (blockIdx.x % 11) * 128;
    const int n0 = blockIdx.y * 128;

    fv16 acc[2][2];
#pragma unroll
    for (int i = 0; i < 2; ++i)
#pragma unroll
        for (int j = 0; j < 2; ++j)
#pragma unroll
            for (int r = 0; r < 16; ++r) acc[i][j][r] = 0.f;

    for (int k0 = 0; k0 < DIM; k0 += 64) {
        __syncthreads();                       // prior iteration's readers done
        // stage A: x fp32 -> bf16, rows m0..m0+127, cols k0..k0+63 (1024 uint4)
#pragma unroll
        for (int u = 0; u < 4; ++u) {
            int i = u * 256 + tid, row = i >> 3, c = i & 7;
            int gm = m0 + row;
            f4 a0 = make_float4(0.f, 0.f, 0.f, 0.f), a1 = a0;
            if (gm < NTOK) {
                const float* xp = x + ((size_t)b * NTOK + gm) * DIM + k0 + c * 8;
                a0 = *(const f4*)xp;
                a1 = *(const f4*)(xp + 4);
            }
            uint4 p;
            p.x = pack2(a0.x, a0.y); p.y = pack2(a0.z, a0.w);
            p.z = pack2(a1.x, a1.y); p.w = pack2(a1.z, a1.w);
            *(uint4*)&As[row * 64 + 8 * (c ^ (row & 7))] = p;
        }
        // stage B: wtb bf16 direct copy, rows n0..n0+127 (1024 uint4)
#pragma unroll
        for (int u = 0; u < 4; ++u) {
            int i = u * 256 + tid, row = i >> 3, c = i & 7;
            uint4 g = *(const uint4*)(wtb + (size_t)(n0 + row) * DIM + k0 + c * 8);
            *(uint4*)&Bsh[row * 64 + 8 * (c ^ (row & 7))] = g;
        }
        __syncthreads();                       // staged tile visible
#pragma unroll
        for (int ki = 0; ki < 4; ++ki) {
            const int swz = ((ql & 7) << 3);
            const int off = (half * 8 + 16 * ki) ^ swz;
            short8 af0 = *(const short8*)&As[(wy * 64 + ql) * 64 + off];
            short8 af1 = *(const short8*)&As[(wy * 64 + 32 + ql) * 64 + off];
            short8 bf0 = *(const short8*)&Bsh[(wx * 64 + ql) * 64 + off];
            short8 bf1 = *(const short8*)&Bsh[(wx * 64 + 32 + ql) * 64 + off];
            acc[0][0] = MFMA(af0, bf0, acc[0][0], 0, 0, 0);
            acc[0][1] = MFMA(af0, bf1, acc[0][1], 0, 0, 0);
            acc[1][0] = MFMA(af1, bf0, acc[1][0], 0, 0, 0);
            acc[1][1] = MFMA(af1, bf1, acc[1][1], 0, 0, 0);
        }
    }

    // epilogue: D col (lane&31) = n, D row ((r&3)+8*(r>>2)+4*half) = m
#pragma unroll
    for (int ri = 0; ri < 2; ++ri)
#pragma unroll
    for (int cj = 0; cj < 2; ++cj) {
        const int n = n0 + wx * 64 + cj * 32 + ql;
        const int which = n >> 9;              // 0 q, 1 k, 2 v (uniform per acc)
        const int hh = (n >> 6) & 7;
        const int dh = n & 63;
        const int bh = b * HEADS + hh;
        const int mb = m0 + wy * 64 + ri * 32 + 4 * half;
        if (which == 0) {
#pragma unroll
            for (int r = 0; r < 16; ++r) {
                int m = mb + (r & 3) + 8 * (r >> 2);
                if (m < NTOK)
                    qbb[((size_t)bh * NTOK + m) * DH + dh] = f2bf(acc[ri][cj][r] * QSCALE);
            }
        } else if (which == 1) {
#pragma unroll
            for (int r = 0; r < 16; ++r) {
                int m = mb + (r & 3) + 8 * (r >> 2);
                if (m < NTOK) {
                    int row = (m < NIMG) ? (m + NGENE) : (m - NIMG);  // concat col order
                    kbb[((size_t)bh * KROWS + row) * DH + dh] = f2bf(acc[ri][cj][r]);
                }
            }
        } else {
#pragma unroll
            for (int r = 0; r < 16; ++r) {
                int m = mb + (r & 3) + 8 * (r >> 2);
                if (m < NTOK)
                    vtb[((size_t)(bh * DH) + dh) * VROW + VPAD + m] = f2bf(acc[ri][cj][r]);
            }
        }
    }
}

// ---------------- kernel 2: fused MFMA attention + Toeplitz conv ----------------
// grid (64, 11): x = bh; y<8 gene out-rows, y>=8 image out-rows. 256 thr = 4 waves,
// each wave owns 32 consecutive out rows. Swapped QK^T (mfma(K,Q)) => logits lane-local.
// K staging: SINGLE LDS buffer, two barriers per tile (sync-stage-sync-compute) —
// provably race-free; no cross-iteration buffer reuse hazards.
__global__ __launch_bounds__(256) void attn_fused(
    const ushort* __restrict__ qbb, const ushort* __restrict__ kbb,
    const ushort* __restrict__ vtb, const float* __restrict__ wres,
    float* __restrict__ out)
{
    __shared__ short Kl[64 * 64];      // one 64x64 bf16 tile, XOR-swizzled chunks
    __shared__ short Pl[4][32 * PLD];  // per-wave P^T, [32 q][64 keys + pad]

    const int tid = threadIdx.x;
    const int lane = tid & 63;
    const int wv = tid >> 6;
    const int half = lane >> 5;
    const int ql = lane & 31;
    const int bh = blockIdx.x, b = bh >> 3, h = bh & 7;
    const int cy = blockIdx.y;
    const bool isGene = cy < 8;
    const int orow0 = (isGene ? cy * 128 : NGENE + (cy - 8) * 128) + wv * 32;
    const int orow_q = orow0 + ql;
    int qtok = isGene ? (NIMG + orow_q) : (orow_q - NGENE);
    if (!isGene && qtok >= NIMG) qtok = 0;   // clamped; rows discarded at write

    // --- Q B-fragments (col=q=lane&31, k=d contiguous 8) ---
    short8 qf[4];
    {
        const ushort* qrow = qbb + ((size_t)bh * NTOK + qtok) * DH;
#pragma unroll
        for (int ki = 0; ki < 4; ++ki)
            qf[ki] = *(const short8*)(qrow + half * 8 + 16 * ki);
    }
    // --- Toeplitz conv A-fragments: T[q][k] = w[k-q] for 0<=k-q<=32 ---
    short8 tf[4];
    {
        const float* wr = wres + h * KERN;
#pragma unroll
        for (int ki = 0; ki < 4; ++ki) {
            short8 v;
#pragma unroll
            for (int e = 0; e < 8; ++e) {
                int k = half * 8 + e + 16 * ki;
                int t = k - ql;
                float wl = (t >= 0 && t <= 32) ? wr[t] : 0.f;
                v[e] = (short)f2bf(wl);
            }
            tf[ki] = v;
        }
    }

    const size_t kbase = (size_t)bh * KROWS * DH;

    // stage tile directly: 512 x uint4 (16B), each thread 2; chunk-swizzled
#define STAGE(tile) {                                                          \
        int i0 = tid,       j0 = i0 >> 3, c0 = i0 & 7;                         \
        int i1 = 256 + tid, j1 = i1 >> 3, c1 = i1 & 7;                         \
        uint4 g0 = *(const uint4*)(kbb + kbase + (size_t)((tile)*64 + j0) * DH + c0 * 8); \
        uint4 g1 = *(const uint4*)(kbb + kbase + (size_t)((tile)*64 + j1) * DH + c1 * 8); \
        *(uint4*)&Kl[j0 * 64 + 8 * (c0 ^ (j0 & 7))] = g0;                      \
        *(uint4*)&Kl[j1 * 64 + 8 * (c1 ^ (j1 & 7))] = g1;                      \
    }
    // QK^T: A = K rows (key = ql / 32+ql), B = Q; swizzled LDS read
#define QKT(s0v, s1v) {                                                        \
        _Pragma("unroll")                                                      \
        for (int r = 0; r < 16; ++r) { s0v[r] = 0.f; s1v[r] = 0.f; }           \
        _Pragma("unroll")                                                      \
        for (int ki = 0; ki < 4; ++ki) {                                       \
            int off = (half * 8 + 16 * ki) ^ ((ql & 7) << 3);                  \
            short8 a0 = *(const short8*)&Kl[ql * 64 + off];                    \
            short8 a1 = *(const short8*)&Kl[(32 + ql) * 64 + off];             \
            s0v = MFMA(a0, qf[ki], s0v, 0, 0, 0);                              \
            s1v = MFMA(a1, qf[ki], s1v, 0, 0, 0);                              \
        }                                                                      \
    }
#define MASK_LAST(s1v) {                                                       \
        _Pragma("unroll")                                                      \
        for (int r = 0; r < 16; ++r) {                                         \
            int off = (r & 3) + 8 * (r >> 2) + 4 * half;                       \
            if (off >= 3) s1v[r] = -1e30f;  /* keys 1312+off >= 1315 */        \
        }                                                                      \
    }
#define TILEMAX(s0v, s1v, tm) {                                                \
        float ta = -1e30f, tb = -1e30f;                                        \
        _Pragma("unroll")                                                      \
        for (int r = 0; r < 16; r += 2) {                                      \
            ta = fmaxf(ta, fmaxf(s0v[r], s0v[r + 1]));                         \
            tb = fmaxf(tb, fmaxf(s1v[r], s1v[r + 1]));                         \
        }                                                                      \
        tm = fmaxf(ta, tb);                                                    \
        tm = fmaxf(tm, __shfl_xor(tm, 32, 64));                                \
    }
    // PV: pack p (bf16) -> Pl [q][key], then A = P rows, B = vtb rows (d), contiguous tok
#define PV(p0, p1, t064, O0, O1) {                                             \
        _Pragma("unroll")                                                      \
        for (int i = 0; i < 4; ++i) {                                          \
            uint2 w0; w0.x = pack2(p0[4*i], p0[4*i+1]); w0.y = pack2(p0[4*i+2], p0[4*i+3]); \
            *(uint2*)&Pl[wv][ql * PLD + 8 * i + 4 * half] = w0;                \
            uint2 w1; w1.x = pack2(p1[4*i], p1[4*i+1]); w1.y = pack2(p1[4*i+2], p1[4*i+3]); \
            *(uint2*)&Pl[wv][ql * PLD + 32 + 8 * i + 4 * half] = w1;           \
        }                                                                      \
        const ushort* vr0 = vtb + ((size_t)(bh * DH) + ql) * VROW + VPAD + (t064); \
        const ushort* vr1 = vr0 + (size_t)32 * VROW;                           \
        _Pragma("unroll")                                                      \
        for (int ki = 0; ki < 4; ++ki) {                                       \
            short8 pa = *(const short8*)&Pl[wv][ql * PLD + half * 8 + 16 * ki]; \
            short8 v0 = *(const short8*)(vr0 + half * 8 + 16 * ki);            \
            short8 v1 = *(const short8*)(vr1 + half * 8 + 16 * ki);            \
            O0 = MFMA(pa, v0, O0, 0, 0, 0);                                    \
            O1 = MFMA(pa, v1, O1, 0, 0, 0);                                    \
        }                                                                      \
    }
    // multiply O rows by per-q value (val lives at lane (q&31))
#define SCALE_O(val, O0, O1) {                                                 \
        _Pragma("unroll")                                                      \
        for (int r = 0; r < 16; ++r) {                                         \
            int qm = (r & 3) + 8 * (r >> 2) + 4 * half;                        \
            float c = __shfl(val, qm, 64);                                     \
            O0[r] *= c; O1[r] *= c;                                            \
        }                                                                      \
    }

    fv16 O0, O1;
#pragma unroll
    for (int r = 0; r < 16; ++r) { O0[r] = 0.f; O1[r] = 0.f; }

    if (isGene) {
        // ---- gene queries: online softmax over all 1315 concat columns ----
        float m = -1e30f, ss = 0.f;
        for (int t = 0; t < NT; ++t) {
            __syncthreads();                  // prior tile's readers done
            STAGE(t);
            __syncthreads();                  // staged tile visible
            fv16 s0v, s1v;
            QKT(s0v, s1v);
            if (t == NT - 1) MASK_LAST(s1v);
            float tm; TILEMAX(s0v, s1v, tm);
            if (__any(tm > m)) {
                float mn = fmaxf(m, tm);
                float corr = __expf(m - mn);
                ss *= corr;
                SCALE_O(corr, O0, O1);
                m = mn;
            }
#pragma unroll
            for (int r = 0; r < 16; ++r) {
                s0v[r] = __expf(s0v[r] - m); ss += s0v[r];
                s1v[r] = __expf(s1v[r] - m); ss += s1v[r];
            }
            PV(s0v, s1v, t * 64, O0, O1);
        }
        float sf = ss + __shfl_xor(ss, 32, 64);
        float inv = 1.0f / sf;
        SCALE_O(inv, O0, O1);
    } else {
        // ---- image queries: two-stage softmax ----
        float m1 = -1e30f, s1s = 0.f, m2 = -1e30f;
        for (int t = 0; t < NT; ++t) {         // pass 1: stats only
            __syncthreads();
            STAGE(t);
            __syncthreads();
            fv16 s0v, s1v;
            QKT(s0v, s1v);
            if (t == NT - 1) MASK_LAST(s1v);
            float tm; TILEMAX(s0v, s1v, tm);
            if (t < 16) {                      // gene-key tiles (cols 0..1023)
                if (__any(tm > m1)) {
                    float mn = fmaxf(m1, tm);
                    s1s *= __expf(m1 - mn);
                    m1 = mn;
                }
#pragma unroll
                for (int r = 0; r < 16; ++r)
                    s1s += __expf(s0v[r] - m1) + __expf(s1v[r] - m1);
            } else {
                m2 = fmaxf(m2, tm);
            }
        }
        s1s += __shfl_xor(s1s, 32, 64);
        float invs1 = 1.0f / s1s;
        float M = fmaxf(invs1, m2);   // max of softmaxed gene block is 1/s1
        float Z = 0.f;
        for (int t = 0; t < NT; ++t) {         // pass 2: accumulate
            __syncthreads();
            STAGE(t);
            __syncthreads();
            fv16 s0v, s1v;
            QKT(s0v, s1v);
            if (t == NT - 1) MASK_LAST(s1v);
            if (t < 16) {
#pragma unroll
                for (int r = 0; r < 16; ++r) {
                    s0v[r] = __expf(__expf(s0v[r] - m1) * invs1 - M); Z += s0v[r];
                    s1v[r] = __expf(__expf(s1v[r] - m1) * invs1 - M); Z += s1v[r];
                }
            } else {
#pragma unroll
                for (int r = 0; r < 16; ++r) {
                    s0v[r] = __expf(s0v[r] - M); Z += s0v[r];
                    s1v[r] = __expf(s1v[r] - M); Z += s1v[r];
                }
            }
            PV(s0v, s1v, t * 64, O0, O1);
        }
        float Zf = Z + __shfl_xor(Z, 32, 64);
        float inv = 1.0f / Zf;
        SCALE_O(inv, O0, O1);
    }

    // ---- fused depthwise conv33 as Toeplitz MFMA + output write ----
    // window tokens [orow0-16, orow0+48); skip waves whose 32 rows are all invalid
    if (isGene || orow0 < NTOK) {
        {
            const ushort* cr0 = vtb + ((size_t)(bh * DH) + ql) * VROW + orow0;  // +VPAD-16 = +0
            const ushort* cr1 = cr0 + (size_t)32 * VROW;
#pragma unroll
            for (int ki = 0; ki < 4; ++ki) {
                short8 v0 = *(const short8*)(cr0 + half * 8 + 16 * ki);
                short8 v1 = *(const short8*)(cr1 + half * 8 + 16 * ki);
                O0 = MFMA(tf[ki], v0, O0, 0, 0, 0);
                O1 = MFMA(tf[ki], v1, O1, 0, 0, 0);
            }
        }
#pragma unroll
        for (int r = 0; r < 16; ++r) {
            int qm = (r & 3) + 8 * (r >> 2) + 4 * half;
            int orow = orow0 + qm;
            if (isGene || orow < NTOK) {
                float* op = out + ((size_t)b * NTOK + orow) * DIM + h * DH + ql;
                op[0]  = O0[r];
                op[32] = O1[r];
            }
        }
    }
#undef STAGE
#undef QKT
#undef MASK_LAST
#undef TILEMAX
#undef PV
#undef SCALE_O
}

extern "C" void kernel_launch(void* const* d_in, const int* in_sizes, int n_in,
                              void* d_out, int out_size, void* d_ws, size_t ws_size,
                              hipStream_t stream)
{
    const float* x     = (const float*)d_in[0];
    const float* w_qkv = (const float*)d_in[1];
    const float* w_res = (const float*)d_in[2];
    float* out = (float*)d_out;

    const size_t qElems = (size_t)BATCH * HEADS * NTOK * DH;    // 5,386,240
    const size_t kElems = (size_t)BATCH * HEADS * KROWS * DH;   // 5,505,024
    const size_t vElems = (size_t)BATCH * HEADS * DH * VROW;    // 5,701,632
    ushort* qbb = (ushort*)d_ws;
    ushort* kbb = qbb + qElems;
    ushort* vtb = kbb + kElems;
    ushort* wtb = vtb + vElems;   // [NQKV][DIM] bf16; total ws ~34.8 MB

    prep<<<dim3(256), 256, 0, stream>>>(w_qkv, kbb, vtb, wtb);
    qkv_gemm<<<dim3(BATCH * 11, NQKV / 128), 256, 0, stream>>>(x, wtb, qbb, kbb, vtb);
    attn_fused<<<dim3(BATCH * HEADS, 11), 256, 0, stream>>>(qbb, kbb, vtb, w_res, out);
}

// Round 9
// 234.704 us; speedup vs baseline: 5.6643x; 1.1197x over previous
//
#include <hip/hip_runtime.h>

#define BATCH 8
#define NTOK 1315
#define DIM 512
#define HEADS 8
#define DH 64
#define NIMG 291
#define NGENE 1024
#define NQKV 1536
#define KERN 33
#define NT 21            // 21 tiles of 64 keys (1315 -> 1344, tail masked)
#define KROWS 1344       // kbb rows per bh (padded to tile multiple)
#define VROW 1392        // vtb row width: 16 left pad + tokens + right pad (zeroed)
#define VPAD 16
#define PLD 72           // Pl row stride in shorts: 144B rows -> short8 reads 16B-aligned
#define LAM 1.4426950408889634f      // 1/ln2
#define QL2 (0.125f * LAM)           // q scale folded with log2 conversion

typedef float4 f4;
typedef __attribute__((ext_vector_type(8)))  short  short8;
typedef __attribute__((ext_vector_type(16))) float  fv16;
#define MFMA __builtin_amdgcn_mfma_f32_32x32x16_bf16

__device__ __forceinline__ ushort f2bf(float f) {   // RNE float->bf16 bits (cold paths)
    union { float f; uint u; } v; v.f = f;
    uint u = v.u;
    uint r = u + 0x7FFFu + ((u >> 16) & 1u);
    return (ushort)(r >> 16);
}
__device__ __forceinline__ uint cvtpk(float lo, float hi) {  // HW pack: lo->[15:0], hi->[31:16]
    uint r;
    asm("v_cvt_pk_bf16_f32 %0, %1, %2" : "=v"(r) : "v"(lo), "v"(hi));
    return r;
}
__device__ __forceinline__ float ex2(float x) {              // single v_exp_f32 (exp2)
    float r;
    asm("v_exp_f32 %0, %1" : "=v"(r) : "v"(x));
    return r;
}

// ---------------- kernel 0a: zero never-written pad regions ----------------
__global__ __launch_bounds__(256) void prep_zero(
    ushort* __restrict__ kbb, ushort* __restrict__ vtb)
{
    const int step = gridDim.x * 256;
    const int tid0 = blockIdx.x * 256 + threadIdx.x;
    const int ktail = 64 * (KROWS - NTOK) * DH;
    for (int i = tid0; i < ktail; i += step) {
        int bh = i / ((KROWS - NTOK) * DH);
        int r  = i % ((KROWS - NTOK) * DH);
        kbb[(size_t)bh * KROWS * DH + (size_t)(NTOK + r / DH) * DH + (r % DH)] = 0;
    }
    // vtb: left pad [0,VPAD) and right zone [VPAD+1344, VROW); middle written by vtrans
    const int rz = VROW - (VPAD + 1344);             // 32
    const int vpadw = VPAD + rz;                     // 48
    const int vtot = 64 * DH * vpadw;
    for (int i = tid0; i < vtot; i += step) {
        int row = i / vpadw, c = i % vpadw;
        int col = (c < VPAD) ? c : (VPAD + 1344 + (c - VPAD));
        vtb[(size_t)row * VROW + col] = 0;
    }
}

// ---------------- kernel 0b: w transpose via LDS tile (both sides coalesced) -------
__global__ __launch_bounds__(256) void wtrans(
    const float* __restrict__ w, ushort* __restrict__ wtb)
{
    __shared__ short T[64][72];
    const int n0 = blockIdx.x * 64;   // 24
    const int k0 = blockIdx.y * 64;   // 8
    const int tid = threadIdx.x;
    {
        int kr = tid >> 2, c0 = (tid & 3) * 16;
        const float* src = w + (size_t)(k0 + kr) * NQKV + n0 + c0;
#pragma unroll
        for (int j = 0; j < 16; j += 4) {
            f4 v = *(const f4*)(src + j);
            T[c0 + j + 0][kr] = (short)f2bf(v.x);
            T[c0 + j + 1][kr] = (short)f2bf(v.y);
            T[c0 + j + 2][kr] = (short)f2bf(v.z);
            T[c0 + j + 3][kr] = (short)f2bf(v.w);
        }
    }
    __syncthreads();
    {
        int nr = tid >> 2, c0 = (tid & 3) * 16;
        ushort* dst = wtb + (size_t)(n0 + nr) * DIM + k0 + c0;
        *(short8*)dst       = *(const short8*)&T[nr][c0];
        *(short8*)(dst + 8) = *(const short8*)&T[nr][c0 + 8];
    }
}

// ---------------- kernel 1: QKV GEMM (bf16 MFMA core) ----------
// q -> qbb bf16 (scaled by QSCALE/ln2); k -> kbb (concat-remapped); v -> vnb row-major.
__global__ __launch_bounds__(256) void qkv_gemm(
    const float* __restrict__ x, const ushort* __restrict__ wtb,
    ushort* __restrict__ qbb, ushort* __restrict__ kbb, ushort* __restrict__ vnb)
{
    __shared__ short As[128 * 64];
    __shared__ short Bsh[128 * 64];

    const int tid = threadIdx.x;
    const int lane = tid & 63;
    const int wv = tid >> 6;
    const int half = lane >> 5;
    const int ql = lane & 31;
    const int wy = wv >> 1, wx = wv & 1;
    const int b  = blockIdx.x / 11;
    const int m0 = (blockIdx.x % 11) * 128;
    const int n0 = blockIdx.y * 128;

    fv16 acc[2][2];
#pragma unroll
    for (int i = 0; i < 2; ++i)
#pragma unroll
        for (int j = 0; j < 2; ++j)
#pragma unroll
            for (int r = 0; r < 16; ++r) acc[i][j][r] = 0.f;

    for (int k0 = 0; k0 < DIM; k0 += 64) {
        __syncthreads();
#pragma unroll
        for (int u = 0; u < 4; ++u) {
            int i = u * 256 + tid, row = i >> 3, c = i & 7;
            int gm = m0 + row;
            f4 a0 = make_float4(0.f, 0.f, 0.f, 0.f), a1 = a0;
            if (gm < NTOK) {
                const float* xp = x + ((size_t)b * NTOK + gm) * DIM + k0 + c * 8;
                a0 = *(const f4*)xp;
                a1 = *(const f4*)(xp + 4);
            }
            uint4 p;
            p.x = cvtpk(a0.x, a0.y); p.y = cvtpk(a0.z, a0.w);
            p.z = cvtpk(a1.x, a1.y); p.w = cvtpk(a1.z, a1.w);
            *(uint4*)&As[row * 64 + 8 * (c ^ (row & 7))] = p;
        }
#pragma unroll
        for (int u = 0; u < 4; ++u) {
            int i = u * 256 + tid, row = i >> 3, c = i & 7;
            uint4 g = *(const uint4*)(wtb + (size_t)(n0 + row) * DIM + k0 + c * 8);
            *(uint4*)&Bsh[row * 64 + 8 * (c ^ (row & 7))] = g;
        }
        __syncthreads();
#pragma unroll
        for (int ki = 0; ki < 4; ++ki) {
            const int off = (half * 8 + 16 * ki) ^ ((ql & 7) << 3);
            short8 af0 = *(const short8*)&As[(wy * 64 + ql) * 64 + off];
            short8 af1 = *(const short8*)&As[(wy * 64 + 32 + ql) * 64 + off];
            short8 bf0 = *(const short8*)&Bsh[(wx * 64 + ql) * 64 + off];
            short8 bf1 = *(const short8*)&Bsh[(wx * 64 + 32 + ql) * 64 + off];
            acc[0][0] = MFMA(af0, bf0, acc[0][0], 0, 0, 0);
            acc[0][1] = MFMA(af0, bf1, acc[0][1], 0, 0, 0);
            acc[1][0] = MFMA(af1, bf0, acc[1][0], 0, 0, 0);
            acc[1][1] = MFMA(af1, bf1, acc[1][1], 0, 0, 0);
        }
    }

    // epilogue: D col (lane&31) = n, D row ((r&3)+8*(r>>2)+4*half) = m
#pragma unroll
    for (int ri = 0; ri < 2; ++ri)
#pragma unroll
    for (int cj = 0; cj < 2; ++cj) {
        const int n = n0 + wx * 64 + cj * 32 + ql;
        const int which = n >> 9;
        const int hh = (n >> 6) & 7;
        const int dh = n & 63;
        const int bh = b * HEADS + hh;
        const int mb = m0 + wy * 64 + ri * 32 + 4 * half;
        if (which == 0) {
#pragma unroll
            for (int r = 0; r < 16; ++r) {
                int m = mb + (r & 3) + 8 * (r >> 2);
                if (m < NTOK)
                    qbb[((size_t)bh * NTOK + m) * DH + dh] = f2bf(acc[ri][cj][r] * QL2);
            }
        } else if (which == 1) {
#pragma unroll
            for (int r = 0; r < 16; ++r) {
                int m = mb + (r & 3) + 8 * (r >> 2);
                if (m < NTOK) {
                    int row = (m < NIMG) ? (m + NGENE) : (m - NIMG);
                    kbb[((size_t)bh * KROWS + row) * DH + dh] = f2bf(acc[ri][cj][r]);
                }
            }
        } else {
#pragma unroll
            for (int r = 0; r < 16; ++r) {
                int m = mb + (r & 3) + 8 * (r >> 2);
                if (m < NTOK)
                    vnb[((size_t)bh * NTOK + m) * DH + dh] = f2bf(acc[ri][cj][r]);
            }
        }
    }
}

// ---------------- kernel 1b: v transpose vnb[bh][tok][dh] -> vtb[bh][dh][VROW] ------
__global__ __launch_bounds__(256) void vtrans(
    const ushort* __restrict__ vnb, ushort* __restrict__ vtb)
{
    __shared__ short T[64][72];
    const int bh = blockIdx.x;
    const int t0 = blockIdx.y * 64;
    const int tid = threadIdx.x;
    {
        int tr = tid >> 2, d0 = (tid & 3) * 16;
        int tok = t0 + tr;
        short8 a, c;
#pragma unroll
        for (int e = 0; e < 8; ++e) { a[e] = 0; c[e] = 0; }
        if (tok < NTOK) {
            const ushort* src = vnb + ((size_t)bh * NTOK + tok) * DH + d0;
            a = *(const short8*)src;
            c = *(const short8*)(src + 8);
        }
#pragma unroll
        for (int e = 0; e < 8; ++e) { T[d0 + e][tr] = a[e]; T[d0 + 8 + e][tr] = c[e]; }
    }
    __syncthreads();
    {
        int dr = tid >> 2, c0 = (tid & 3) * 16;
        ushort* dst = vtb + ((size_t)(bh * DH) + dr) * VROW + VPAD + t0 + c0;
        *(short8*)dst       = *(const short8*)&T[dr][c0];
        *(short8*)(dst + 8) = *(const short8*)&T[dr][c0 + 8];
    }
}

// ---------------- kernel 2: fused MFMA attention + Toeplitz conv ----------------
// grid (64, 11): y<3 image chunks (longest-first), y>=3 gene chunks. 4 waves x 32 q.
// All logits in log2 domain (q pre-scaled by QSCALE/ln2): every exp is one v_exp_f32.
// Staging: single Kl buffer, T14 split (load-early / write-after-readers-barrier).
__global__ __launch_bounds__(256) void attn_fused(
    const ushort* __restrict__ qbb, const ushort* __restrict__ kbb,
    const ushort* __restrict__ vtb, const float* __restrict__ wres,
    float* __restrict__ out)
{
    __shared__ short Kl[64 * 64];
    __shared__ short Pl[4][32 * PLD];

    const int tid = threadIdx.x;
    const int lane = tid & 63;
    const int wv = tid >> 6;
    const int half = lane >> 5;
    const int ql = lane & 31;
    const int bh = blockIdx.x, b = bh >> 3, h = bh & 7;
    const int cy = blockIdx.y;
    const bool isGene = cy >= 3;
    const int orow0 = (isGene ? (cy - 3) * 128 : NGENE + cy * 128) + wv * 32;
    const int orow_q = orow0 + ql;
    int qtok = isGene ? (NIMG + orow_q) : (orow_q - NGENE);
    if (!isGene && qtok >= NIMG) qtok = 0;   // clamped; rows discarded at write

    short8 qf[4];
    {
        const ushort* qrow = qbb + ((size_t)bh * NTOK + qtok) * DH;
#pragma unroll
        for (int ki = 0; ki < 4; ++ki)
            qf[ki] = *(const short8*)(qrow + half * 8 + 16 * ki);
    }
    short8 tf[4];   // Toeplitz conv A-fragments: T[q][k] = w[k-q], 0<=k-q<=32
    {
        const float* wr = wres + h * KERN;
#pragma unroll
        for (int ki = 0; ki < 4; ++ki) {
            short8 v;
#pragma unroll
            for (int e = 0; e < 8; ++e) {
                int k = half * 8 + e + 16 * ki;
                int t = k - ql;
                float wl = (t >= 0 && t <= 32) ? wr[t] : 0.f;
                v[e] = (short)f2bf(wl);
            }
            tf[ki] = v;
        }
    }

    const size_t kbase = (size_t)bh * KROWS * DH;
    uint4 sg0, sg1;

#define STAGE_LOAD(tile) {                                                     \
        int i0 = tid,       j0 = i0 >> 3, c0 = i0 & 7;                         \
        int i1 = 256 + tid, j1 = i1 >> 3, c1 = i1 & 7;                         \
        sg0 = *(const uint4*)(kbb + kbase + (size_t)((tile)*64 + j0) * DH + c0 * 8); \
        sg1 = *(const uint4*)(kbb + kbase + (size_t)((tile)*64 + j1) * DH + c1 * 8); \
    }
#define STAGE_WRITE() {                                                        \
        int i0 = tid,       j0 = i0 >> 3, c0 = i0 & 7;                         \
        int i1 = 256 + tid, j1 = i1 >> 3, c1 = i1 & 7;                         \
        *(uint4*)&Kl[j0 * 64 + 8 * (c0 ^ (j0 & 7))] = sg0;                     \
        *(uint4*)&Kl[j1 * 64 + 8 * (c1 ^ (j1 & 7))] = sg1;                     \
    }
#define QKT(s0v, s1v) {                                                        \
        _Pragma("unroll")                                                      \
        for (int r = 0; r < 16; ++r) { s0v[r] = 0.f; s1v[r] = 0.f; }           \
        _Pragma("unroll")                                                      \
        for (int ki = 0; ki < 4; ++ki) {                                       \
            int off = (half * 8 + 16 * ki) ^ ((ql & 7) << 3);                  \
            short8 a0 = *(const short8*)&Kl[ql * 64 + off];                    \
            short8 a1 = *(const short8*)&Kl[(32 + ql) * 64 + off];             \
            s0v = MFMA(a0, qf[ki], s0v, 0, 0, 0);                              \
            s1v = MFMA(a1, qf[ki], s1v, 0, 0, 0);                              \
        }                                                                      \
    }
#define MASK_LAST(s1v) {                                                       \
        _Pragma("unroll")                                                      \
        for (int r = 0; r < 16; ++r) {                                         \
            int off = (r & 3) + 8 * (r >> 2) + 4 * half;                       \
            if (off >= 3) s1v[r] = -1e30f;  /* keys 1312+off >= 1315 */        \
        }                                                                      \
    }
#define TILEMAX(s0v, s1v, tm) {                                                \
        float ta = -1e30f, tb = -1e30f;                                        \
        _Pragma("unroll")                                                      \
        for (int r = 0; r < 16; r += 2) {                                      \
            ta = fmaxf(ta, fmaxf(s0v[r], s0v[r + 1]));                         \
            tb = fmaxf(tb, fmaxf(s1v[r], s1v[r + 1]));                         \
        }                                                                      \
        tm = fmaxf(ta, tb);                                                    \
        tm = fmaxf(tm, __shfl_xor(tm, 32, 64));                                \
    }
#define PV(p0, p1, t064, O0, O1) {                                             \
        _Pragma("unroll")                                                      \
        for (int i = 0; i < 4; ++i) {                                          \
            uint2 w0; w0.x = cvtpk(p0[4*i], p0[4*i+1]); w0.y = cvtpk(p0[4*i+2], p0[4*i+3]); \
            *(uint2*)&Pl[wv][ql * PLD + 8 * i + 4 * half] = w0;                \
            uint2 w1; w1.x = cvtpk(p1[4*i], p1[4*i+1]); w1.y = cvtpk(p1[4*i+2], p1[4*i+3]); \
            *(uint2*)&Pl[wv][ql * PLD + 32 + 8 * i + 4 * half] = w1;           \
        }                                                                      \
        const ushort* vr0 = vtb + ((size_t)(bh * DH) + ql) * VROW + VPAD + (t064); \
        const ushort* vr1 = vr0 + (size_t)32 * VROW;                           \
        _Pragma("unroll")                                                      \
        for (int ki = 0; ki < 4; ++ki) {                                       \
            short8 pa = *(const short8*)&Pl[wv][ql * PLD + half * 8 + 16 * ki]; \
            short8 v0 = *(const short8*)(vr0 + half * 8 + 16 * ki);            \
            short8 v1 = *(const short8*)(vr1 + half * 8 + 16 * ki);            \
            O0 = MFMA(pa, v0, O0, 0, 0, 0);                                    \
            O1 = MFMA(pa, v1, O1, 0, 0, 0);                                    \
        }                                                                      \
    }
#define SCALE_O(val, O0, O1) {                                                 \
        _Pragma("unroll")                                                      \
        for (int r = 0; r < 16; ++r) {                                         \
            int qm = (r & 3) + 8 * (r >> 2) + 4 * half;                        \
            float c = __shfl(val, qm, 64);                                     \
            O0[r] *= c; O1[r] *= c;                                            \
        }                                                                      \
    }

    fv16 O0, O1;
#pragma unroll
    for (int r = 0; r < 16; ++r) { O0[r] = 0.f; O1[r] = 0.f; }

    if (isGene) {
        // ---- gene queries: online softmax (log2 domain) over 1315 concat cols ----
        float m = -1e30f, ss = 0.f;
        STAGE_LOAD(0); STAGE_WRITE(); __syncthreads();
        for (int t = 0; t < NT; ++t) {
            const bool more = (t + 1 < NT);
            if (more) STAGE_LOAD(t + 1);
            fv16 s0v, s1v;
            QKT(s0v, s1v);
            __syncthreads();                 // all QKT reads of Kl done
            if (more) STAGE_WRITE();         // overwrite Kl; visible after next barrier
            if (t == NT - 1) MASK_LAST(s1v);
            float tm; TILEMAX(s0v, s1v, tm);
            if (__any(tm > m)) {
                float mn = fmaxf(m, tm);
                float corr = ex2(m - mn);
                ss *= corr;
                SCALE_O(corr, O0, O1);
                m = mn;
            }
#pragma unroll
            for (int r = 0; r < 16; ++r) {
                s0v[r] = ex2(s0v[r] - m); ss += s0v[r];
                s1v[r] = ex2(s1v[r] - m); ss += s1v[r];
            }
            PV(s0v, s1v, t * 64, O0, O1);
            __syncthreads();
        }
        float sf = ss + __shfl_xor(ss, 32, 64);
        float inv = 1.0f / sf;
        SCALE_O(inv, O0, O1);
    } else {
        // ---- image queries: two-stage softmax (log2 domain) ----
        float m1 = -1e30f, s1s = 0.f, m2p = -1e30f;
        STAGE_LOAD(0); STAGE_WRITE(); __syncthreads();
        for (int t = 0; t < NT; ++t) {       // pass 1: stats only
            const bool more = (t + 1 < NT);
            if (more) STAGE_LOAD(t + 1);
            fv16 s0v, s1v;
            QKT(s0v, s1v);
            __syncthreads();
            if (more) STAGE_WRITE();
            if (t == NT - 1) MASK_LAST(s1v);
            float tm; TILEMAX(s0v, s1v, tm);
            if (t < 16) {
                if (__any(tm > m1)) {
                    float mn = fmaxf(m1, tm);
                    s1s *= ex2(m1 - mn);
                    m1 = mn;
                }
#pragma unroll
                for (int r = 0; r < 16; ++r)
                    s1s += ex2(s0v[r] - m1) + ex2(s1v[r] - m1);
            } else {
                m2p = fmaxf(m2p, tm);
            }
            __syncthreads();
        }
        s1s += __shfl_xor(s1s, 32, 64);
        float invs1 = 1.0f / s1s;
        // true M = max(1/s1, m2); log2-domain M2 = LAM*M; gene weight:
        // LAM*p = exp2(l' - m1 + c1), c1 = log2(LAM/s1)  =>  shifted max m1c = m1 - c1.
        float c1 = __log2f(LAM * invs1);
        float m1c = m1 - c1;                 // FIX: was m1 + c1 (sign error -> inf -> NaN)
        float M2 = fmaxf(LAM * invs1, m2p);
        float Z = 0.f;
        STAGE_LOAD(0); STAGE_WRITE(); __syncthreads();
        for (int t = 0; t < NT; ++t) {       // pass 2: accumulate
            const bool more = (t + 1 < NT);
            if (more) STAGE_LOAD(t + 1);
            fv16 s0v, s1v;
            QKT(s0v, s1v);
            __syncthreads();
            if (more) STAGE_WRITE();
            if (t == NT - 1) MASK_LAST(s1v);
            if (t < 16) {
#pragma unroll
                for (int r = 0; r < 16; ++r) {
                    s0v[r] = ex2(ex2(s0v[r] - m1c) - M2); Z += s0v[r];
                    s1v[r] = ex2(ex2(s1v[r] - m1c) - M2); Z += s1v[r];
                }
            } else {
#pragma unroll
                for (int r = 0; r < 16; ++r) {
                    s0v[r] = ex2(s0v[r] - M2); Z += s0v[r];
                    s1v[r] = ex2(s1v[r] - M2); Z += s1v[r];
                }
            }
            PV(s0v, s1v, t * 64, O0, O1);
            __syncthreads();
        }
        float Zf = Z + __shfl_xor(Z, 32, 64);
        float inv = 1.0f / Zf;
        SCALE_O(inv, O0, O1);
    }

    // ---- fused depthwise conv33 as Toeplitz MFMA + output write ----
    if (isGene || orow0 < NTOK) {
        {
            const ushort* cr0 = vtb + ((size_t)(bh * DH) + ql) * VROW + orow0;  // +VPAD-16
            const ushort* cr1 = cr0 + (size_t)32 * VROW;
#pragma unroll
            for (int ki = 0; ki < 4; ++ki) {
                short8 v0 = *(const short8*)(cr0 + half * 8 + 16 * ki);
                short8 v1 = *(const short8*)(cr1 + half * 8 + 16 * ki);
                O0 = MFMA(tf[ki], v0, O0, 0, 0, 0);
                O1 = MFMA(tf[ki], v1, O1, 0, 0, 0);
            }
        }
#pragma unroll
        for (int r = 0; r < 16; ++r) {
            int qm = (r & 3) + 8 * (r >> 2) + 4 * half;
            int orow = orow0 + qm;
            if (isGene || orow < NTOK) {
                float* op = out + ((size_t)b * NTOK + orow) * DIM + h * DH + ql;
                op[0]  = O0[r];
                op[32] = O1[r];
            }
        }
    }
#undef STAGE_LOAD
#undef STAGE_WRITE
#undef QKT
#undef MASK_LAST
#undef TILEMAX
#undef PV
#undef SCALE_O
}

extern "C" void kernel_launch(void* const* d_in, const int* in_sizes, int n_in,
                              void* d_out, int out_size, void* d_ws, size_t ws_size,
                              hipStream_t stream)
{
    const float* x     = (const float*)d_in[0];
    const float* w_qkv = (const float*)d_in[1];
    const float* w_res = (const float*)d_in[2];
    float* out = (float*)d_out;

    const size_t qElems = (size_t)BATCH * HEADS * NTOK * DH;    // 5,386,240
    const size_t kElems = (size_t)BATCH * HEADS * KROWS * DH;   // 5,505,024
    const size_t vElems = (size_t)BATCH * HEADS * DH * VROW;    // 5,701,632
    ushort* qbb = (ushort*)d_ws;
    ushort* kbb = qbb + qElems;
    ushort* vnb = kbb + kElems;          // row-major v staging
    ushort* vtb = vnb + qElems;
    ushort* wtb = vtb + vElems;          // [NQKV][DIM] bf16; total ws ~45.5 MB

    prep_zero<<<dim3(64), 256, 0, stream>>>(kbb, vtb);
    wtrans<<<dim3(NQKV / 64, DIM / 64), 256, 0, stream>>>(w_qkv, wtb);
    qkv_gemm<<<dim3(BATCH * 11, NQKV / 128), 256, 0, stream>>>(x, wtb, qbb, kbb, vnb);
    vtrans<<<dim3(BATCH * HEADS, NT), 256, 0, stream>>>(vnb, vtb);
    attn_fused<<<dim3(BATCH * HEADS, 11), 256, 0, stream>>>(qbb, kbb, vtb, w_res, out);
}

// Round 11
// 229.974 us; speedup vs baseline: 5.7808x; 1.0206x over previous
//
#include <hip/hip_runtime.h>

#define BATCH 8
#define NTOK 1315
#define DIM 512
#define HEADS 8
#define DH 64
#define NIMG 291
#define NGENE 1024
#define NQKV 1536
#define KERN 33
#define NT 21            // 21 tiles of 64 keys (1315 -> 1344, tail masked)
#define KROWS 1344       // kbb rows per bh (padded to tile multiple)
#define VROW 1392        // vtb row width: 16 left pad + tokens + right pad (zeroed)
#define VPAD 16
#define PLD 72           // Pl row stride in shorts: 144B rows -> short8 reads 16B-aligned
#define LAM 1.4426950408889634f      // 1/ln2
#define QL2 (0.125f * LAM)           // q scale folded with log2 conversion

typedef float4 f4;
typedef __attribute__((ext_vector_type(8)))  short  short8;
typedef __attribute__((ext_vector_type(16))) float  fv16;
#define MFMA __builtin_amdgcn_mfma_f32_32x32x16_bf16

__device__ __forceinline__ ushort f2bf(float f) {   // RNE float->bf16 bits (cold paths)
    union { float f; uint u; } v; v.f = f;
    uint u = v.u;
    uint r = u + 0x7FFFu + ((u >> 16) & 1u);
    return (ushort)(r >> 16);
}
__device__ __forceinline__ uint cvtpk(float lo, float hi) {  // HW pack: lo->[15:0], hi->[31:16]
    uint r;
    asm("v_cvt_pk_bf16_f32 %0, %1, %2" : "=v"(r) : "v"(lo), "v"(hi));
    return r;
}
__device__ __forceinline__ float ex2(float x) {              // single v_exp_f32 (exp2)
    float r;
    asm("v_exp_f32 %0, %1" : "=v"(r) : "v"(x));
    return r;
}

// ---------------- kernel 0a: zero never-written pad regions ----------------
__global__ __launch_bounds__(256) void prep_zero(
    ushort* __restrict__ kbb, ushort* __restrict__ vtb)
{
    const int step = gridDim.x * 256;
    const int tid0 = blockIdx.x * 256 + threadIdx.x;
    const int ktail = 64 * (KROWS - NTOK) * DH;
    for (int i = tid0; i < ktail; i += step) {
        int bh = i / ((KROWS - NTOK) * DH);
        int r  = i % ((KROWS - NTOK) * DH);
        kbb[(size_t)bh * KROWS * DH + (size_t)(NTOK + r / DH) * DH + (r % DH)] = 0;
    }
    const int rz = VROW - (VPAD + 1344);             // 32
    const int vpadw = VPAD + rz;                     // 48
    const int vtot = 64 * DH * vpadw;
    for (int i = tid0; i < vtot; i += step) {
        int row = i / vpadw, c = i % vpadw;
        int col = (c < VPAD) ? c : (VPAD + 1344 + (c - VPAD));
        vtb[(size_t)row * VROW + col] = 0;
    }
}

// ---------------- kernel 0b: w transpose via LDS tile (both sides coalesced) -------
__global__ __launch_bounds__(256) void wtrans(
    const float* __restrict__ w, ushort* __restrict__ wtb)
{
    __shared__ short T[64][72];
    const int n0 = blockIdx.x * 64;
    const int k0 = blockIdx.y * 64;
    const int tid = threadIdx.x;
    {
        int kr = tid >> 2, c0 = (tid & 3) * 16;
        const float* src = w + (size_t)(k0 + kr) * NQKV + n0 + c0;
#pragma unroll
        for (int j = 0; j < 16; j += 4) {
            f4 v = *(const f4*)(src + j);
            T[c0 + j + 0][kr] = (short)f2bf(v.x);
            T[c0 + j + 1][kr] = (short)f2bf(v.y);
            T[c0 + j + 2][kr] = (short)f2bf(v.z);
            T[c0 + j + 3][kr] = (short)f2bf(v.w);
        }
    }
    __syncthreads();
    {
        int nr = tid >> 2, c0 = (tid & 3) * 16;
        ushort* dst = wtb + (size_t)(n0 + nr) * DIM + k0 + c0;
        *(short8*)dst       = *(const short8*)&T[nr][c0];
        *(short8*)(dst + 8) = *(const short8*)&T[nr][c0 + 8];
    }
}

// ---------------- kernel 1: QKV GEMM (bf16 MFMA core) ----------
__global__ __launch_bounds__(256) void qkv_gemm(
    const float* __restrict__ x, const ushort* __restrict__ wtb,
    ushort* __restrict__ qbb, ushort* __restrict__ kbb, ushort* __restrict__ vnb)
{
    __shared__ short As[128 * 64];
    __shared__ short Bsh[128 * 64];

    const int tid = threadIdx.x;
    const int lane = tid & 63;
    const int wv = tid >> 6;
    const int half = lane >> 5;
    const int ql = lane & 31;
    const int wy = wv >> 1, wx = wv & 1;
    const int b  = blockIdx.x / 11;
    const int m0 = (blockIdx.x % 11) * 128;
    const int n0 = blockIdx.y * 128;

    fv16 acc[2][2];
#pragma unroll
    for (int i = 0; i < 2; ++i)
#pragma unroll
        for (int j = 0; j < 2; ++j)
#pragma unroll
            for (int r = 0; r < 16; ++r) acc[i][j][r] = 0.f;

    for (int k0 = 0; k0 < DIM; k0 += 64) {
        __syncthreads();
#pragma unroll
        for (int u = 0; u < 4; ++u) {
            int i = u * 256 + tid, row = i >> 3, c = i & 7;
            int gm = m0 + row;
            f4 a0 = make_float4(0.f, 0.f, 0.f, 0.f), a1 = a0;
            if (gm < NTOK) {
                const float* xp = x + ((size_t)b * NTOK + gm) * DIM + k0 + c * 8;
                a0 = *(const f4*)xp;
                a1 = *(const f4*)(xp + 4);
            }
            uint4 p;
            p.x = cvtpk(a0.x, a0.y); p.y = cvtpk(a0.z, a0.w);
            p.z = cvtpk(a1.x, a1.y); p.w = cvtpk(a1.z, a1.w);
            *(uint4*)&As[row * 64 + 8 * (c ^ (row & 7))] = p;
        }
#pragma unroll
        for (int u = 0; u < 4; ++u) {
            int i = u * 256 + tid, row = i >> 3, c = i & 7;
            uint4 g = *(const uint4*)(wtb + (size_t)(n0 + row) * DIM + k0 + c * 8);
            *(uint4*)&Bsh[row * 64 + 8 * (c ^ (row & 7))] = g;
        }
        __syncthreads();
#pragma unroll
        for (int ki = 0; ki < 4; ++ki) {
            const int off = (half * 8 + 16 * ki) ^ ((ql & 7) << 3);
            short8 af0 = *(const short8*)&As[(wy * 64 + ql) * 64 + off];
            short8 af1 = *(const short8*)&As[(wy * 64 + 32 + ql) * 64 + off];
            short8 bf0 = *(const short8*)&Bsh[(wx * 64 + ql) * 64 + off];
            short8 bf1 = *(const short8*)&Bsh[(wx * 64 + 32 + ql) * 64 + off];
            acc[0][0] = MFMA(af0, bf0, acc[0][0], 0, 0, 0);
            acc[0][1] = MFMA(af0, bf1, acc[0][1], 0, 0, 0);
            acc[1][0] = MFMA(af1, bf0, acc[1][0], 0, 0, 0);
            acc[1][1] = MFMA(af1, bf1, acc[1][1], 0, 0, 0);
        }
    }

#pragma unroll
    for (int ri = 0; ri < 2; ++ri)
#pragma unroll
    for (int cj = 0; cj < 2; ++cj) {
        const int n = n0 + wx * 64 + cj * 32 + ql;
        const int which = n >> 9;
        const int hh = (n >> 6) & 7;
        const int dh = n & 63;
        const int bh = b * HEADS + hh;
        const int mb = m0 + wy * 64 + ri * 32 + 4 * half;
        if (which == 0) {
#pragma unroll
            for (int r = 0; r < 16; ++r) {
                int m = mb + (r & 3) + 8 * (r >> 2);
                if (m < NTOK)
                    qbb[((size_t)bh * NTOK + m) * DH + dh] = f2bf(acc[ri][cj][r] * QL2);
            }
        } else if (which == 1) {
#pragma unroll
            for (int r = 0; r < 16; ++r) {
                int m = mb + (r & 3) + 8 * (r >> 2);
                if (m < NTOK) {
                    int row = (m < NIMG) ? (m + NGENE) : (m - NIMG);
                    kbb[((size_t)bh * KROWS + row) * DH + dh] = f2bf(acc[ri][cj][r]);
                }
            }
        } else {
#pragma unroll
            for (int r = 0; r < 16; ++r) {
                int m = mb + (r & 3) + 8 * (r >> 2);
                if (m < NTOK)
                    vnb[((size_t)bh * NTOK + m) * DH + dh] = f2bf(acc[ri][cj][r]);
            }
        }
    }
}

// ---------------- kernel 1b: v transpose vnb[bh][tok][dh] -> vtb[bh][dh][VROW] ------
__global__ __launch_bounds__(256) void vtrans(
    const ushort* __restrict__ vnb, ushort* __restrict__ vtb)
{
    __shared__ short T[64][72];
    const int bh = blockIdx.x;
    const int t0 = blockIdx.y * 64;
    const int tid = threadIdx.x;
    {
        int tr = tid >> 2, d0 = (tid & 3) * 16;
        int tok = t0 + tr;
        short8 a, c;
#pragma unroll
        for (int e = 0; e < 8; ++e) { a[e] = 0; c[e] = 0; }
        if (tok < NTOK) {
            const ushort* src = vnb + ((size_t)bh * NTOK + tok) * DH + d0;
            a = *(const short8*)src;
            c = *(const short8*)(src + 8);
        }
#pragma unroll
        for (int e = 0; e < 8; ++e) { T[d0 + e][tr] = a[e]; T[d0 + 8 + e][tr] = c[e]; }
    }
    __syncthreads();
    {
        int dr = tid >> 2, c0 = (tid & 3) * 16;
        ushort* dst = vtb + ((size_t)(bh * DH) + dr) * VROW + VPAD + t0 + c0;
        *(short8*)dst       = *(const short8*)&T[dr][c0];
        *(short8*)(dst + 8) = *(const short8*)&T[dr][c0 + 8];
    }
}

// ---------------- kernel 1c: vsum[bh][d] = sum_{tok<1024} v[bh][tok][d] ------------
// Gene-column V row-sum (first-order Taylor term for image two-stage softmax).
__global__ __launch_bounds__(256) void vsum_k(
    const ushort* __restrict__ vnb, float* __restrict__ vsum)
{
    __shared__ float red[4][64];
    const int bh = blockIdx.x;
    const int tid = threadIdx.x;
    const int d = tid & 63, part = tid >> 6;
    float s = 0.f;
    const ushort* src = vnb + ((size_t)bh * NTOK + part * 256) * DH + d;
    for (int r = 0; r < 256; ++r) {
        union { uint u; float f; } cv; cv.u = ((uint)src[(size_t)r * DH]) << 16;
        s += cv.f;
    }
    red[part][d] = s;
    __syncthreads();
    if (tid < 64)
        vsum[bh * 64 + tid] = red[0][tid] + red[1][tid] + red[2][tid] + red[3][tid];
}

// ---------------- kernel 2: fused MFMA attention + Toeplitz conv ----------------
// grid (64, 11): y<3 image chunks, y>=3 gene chunks. 4 waves x 32 q. SINGLE pass for
// both: unified online softmax in log2 domain; image path injects a boundary at the
// gene/img tile edge (t==16): gene part collapses via 1st-order Taylor
// exp(g-M) ~= e^-M (1+g), g<=1/s1~2e-3 (error ~1e-6) => O <- e2m*(Vsum + O/s1),
// ss <- 512.5*e2m per half, running max m <- LAM/s1; img tiles continue online.
__global__ __launch_bounds__(256) void attn_fused(
    const ushort* __restrict__ qbb, const ushort* __restrict__ kbb,
    const ushort* __restrict__ vtb, const float* __restrict__ wres,
    const float* __restrict__ vsum, float* __restrict__ out)
{
    __shared__ short Kl[64 * 64];
    __shared__ short Pl[4][32 * PLD];

    const int tid = threadIdx.x;
    const int lane = tid & 63;
    const int wv = tid >> 6;
    const int half = lane >> 5;
    const int ql = lane & 31;
    const int bh = blockIdx.x, b = bh >> 3, h = bh & 7;
    const int cy = blockIdx.y;
    const bool isGene = cy >= 3;
    const int orow0 = (isGene ? (cy - 3) * 128 : NGENE + cy * 128) + wv * 32;
    const int orow_q = orow0 + ql;
    int qtok = isGene ? (NIMG + orow_q) : (orow_q - NGENE);
    if (!isGene && qtok >= NIMG) qtok = 0;   // clamped; rows discarded at write

    short8 qf[4];
    {
        const ushort* qrow = qbb + ((size_t)bh * NTOK + qtok) * DH;
#pragma unroll
        for (int ki = 0; ki < 4; ++ki)
            qf[ki] = *(const short8*)(qrow + half * 8 + 16 * ki);
    }
    short8 tf[4];   // Toeplitz conv A-fragments: T[q][k] = w[k-q], 0<=k-q<=32
    {
        const float* wr = wres + h * KERN;
#pragma unroll
        for (int ki = 0; ki < 4; ++ki) {
            short8 v;
#pragma unroll
            for (int e = 0; e < 8; ++e) {
                int k = half * 8 + e + 16 * ki;
                int t = k - ql;
                float wl = (t >= 0 && t <= 32) ? wr[t] : 0.f;
                v[e] = (short)f2bf(wl);
            }
            tf[ki] = v;
        }
    }
    float vs0 = 0.f, vs1 = 0.f;
    if (!isGene) { vs0 = vsum[bh * 64 + ql]; vs1 = vsum[bh * 64 + 32 + ql]; }

    const size_t kbase = (size_t)bh * KROWS * DH;
    uint4 sg0, sg1;

#define STAGE_LOAD(tile) {                                                     \
        int i0 = tid,       j0 = i0 >> 3, c0 = i0 & 7;                         \
        int i1 = 256 + tid, j1 = i1 >> 3, c1 = i1 & 7;                         \
        sg0 = *(const uint4*)(kbb + kbase + (size_t)((tile)*64 + j0) * DH + c0 * 8); \
        sg1 = *(const uint4*)(kbb + kbase + (size_t)((tile)*64 + j1) * DH + c1 * 8); \
    }
#define STAGE_WRITE() {                                                        \
        int i0 = tid,       j0 = i0 >> 3, c0 = i0 & 7;                         \
        int i1 = 256 + tid, j1 = i1 >> 3, c1 = i1 & 7;                         \
        *(uint4*)&Kl[j0 * 64 + 8 * (c0 ^ (j0 & 7))] = sg0;                     \
        *(uint4*)&Kl[j1 * 64 + 8 * (c1 ^ (j1 & 7))] = sg1;                     \
    }
#define QKT(s0v, s1v) {                                                        \
        _Pragma("unroll")                                                      \
        for (int r = 0; r < 16; ++r) { s0v[r] = 0.f; s1v[r] = 0.f; }           \
        _Pragma("unroll")                                                      \
        for (int ki = 0; ki < 4; ++ki) {                                       \
            int off = (half * 8 + 16 * ki) ^ ((ql & 7) << 3);                  \
            short8 a0 = *(const short8*)&Kl[ql * 64 + off];                    \
            short8 a1 = *(const short8*)&Kl[(32 + ql) * 64 + off];             \
            s0v = MFMA(a0, qf[ki], s0v, 0, 0, 0);                              \
            s1v = MFMA(a1, qf[ki], s1v, 0, 0, 0);                              \
        }                                                                      \
    }
#define MASK_LAST(s1v) {                                                       \
        _Pragma("unroll")                                                      \
        for (int r = 0; r < 16; ++r) {                                         \
            int off = (r & 3) + 8 * (r >> 2) + 4 * half;                       \
            if (off >= 3) s1v[r] = -1e30f;  /* keys 1312+off >= 1315 */        \
        }                                                                      \
    }
#define TILEMAX(s0v, s1v, tm) {                                                \
        float ta = -1e30f, tb = -1e30f;                                        \
        _Pragma("unroll")                                                      \
        for (int r = 0; r < 16; r += 2) {                                      \
            ta = fmaxf(ta, fmaxf(s0v[r], s0v[r + 1]));                         \
            tb = fmaxf(tb, fmaxf(s1v[r], s1v[r + 1]));                         \
        }                                                                      \
        tm = fmaxf(ta, tb);                                                    \
        tm = fmaxf(tm, __shfl_xor(tm, 32, 64));                                \
    }
#define PV(p0, p1, t064, O0, O1) {                                             \
        _Pragma("unroll")                                                      \
        for (int i = 0; i < 4; ++i) {                                          \
            uint2 w0; w0.x = cvtpk(p0[4*i], p0[4*i+1]); w0.y = cvtpk(p0[4*i+2], p0[4*i+3]); \
            *(uint2*)&Pl[wv][ql * PLD + 8 * i + 4 * half] = w0;                \
            uint2 w1; w1.x = cvtpk(p1[4*i], p1[4*i+1]); w1.y = cvtpk(p1[4*i+2], p1[4*i+3]); \
            *(uint2*)&Pl[wv][ql * PLD + 32 + 8 * i + 4 * half] = w1;           \
        }                                                                      \
        const ushort* vr0 = vtb + ((size_t)(bh * DH) + ql) * VROW + VPAD + (t064); \
        const ushort* vr1 = vr0 + (size_t)32 * VROW;                           \
        _Pragma("unroll")                                                      \
        for (int ki = 0; ki < 4; ++ki) {                                       \
            short8 pa = *(const short8*)&Pl[wv][ql * PLD + half * 8 + 16 * ki]; \
            short8 v0 = *(const short8*)(vr0 + half * 8 + 16 * ki);            \
            short8 v1 = *(const short8*)(vr1 + half * 8 + 16 * ki);            \
            O0 = MFMA(pa, v0, O0, 0, 0, 0);                                    \
            O1 = MFMA(pa, v1, O1, 0, 0, 0);                                    \
        }                                                                      \
    }
#define SCALE_O(val, O0, O1) {                                                 \
        _Pragma("unroll")                                                      \
        for (int r = 0; r < 16; ++r) {                                         \
            int qm = (r & 3) + 8 * (r >> 2) + 4 * half;                        \
            float c = __shfl(val, qm, 64);                                     \
            O0[r] *= c; O1[r] *= c;                                            \
        }                                                                      \
    }

    fv16 O0, O1;
#pragma unroll
    for (int r = 0; r < 16; ++r) { O0[r] = 0.f; O1[r] = 0.f; }

    // ---- unified online softmax loop (log2 domain), per-query scalars at lane q ----
    float m = -1e30f, ss = 0.f;
    STAGE_LOAD(0); STAGE_WRITE(); __syncthreads();
    for (int t = 0; t < NT; ++t) {
        const bool more = (t + 1 < NT);
        if (more) STAGE_LOAD(t + 1);
        fv16 s0v, s1v;
        QKT(s0v, s1v);
        __syncthreads();                 // all QKT reads of Kl done
        if (more) STAGE_WRITE();         // overwrite Kl; visible after next barrier
        if (t == NT - 1) MASK_LAST(s1v);
        if (!isGene && t == 16) {
            // gene/img boundary: collapse softmaxed-gene part (1st-order Taylor)
            float s1f = ss + __shfl_xor(ss, 32, 64);   // s1 for query ql
            float invs1 = 1.0f / s1f;
            float mnew = LAM * invs1;                  // log2-domain max = LAM*(1/s1)
            float e2m = ex2(-mnew);                    // exp(-1/s1)
            float sc = e2m * invs1;
#pragma unroll
            for (int r = 0; r < 16; ++r) {
                int qm = (r & 3) + 8 * (r >> 2) + 4 * half;
                float scr = __shfl(sc, qm, 64);
                float e2r = __shfl(e2m, qm, 64);
                O0[r] = O0[r] * scr + e2r * vs0;
                O1[r] = O1[r] * scr + e2r * vs1;
            }
            ss = 512.5f * e2m;                          // half of 1025*e2m per lane
            m = mnew;
        }
        float tm; TILEMAX(s0v, s1v, tm);
        if (__any(tm > m)) {
            float mn = fmaxf(m, tm);
            float corr = ex2(m - mn);
            ss *= corr;
            SCALE_O(corr, O0, O1);
            m = mn;
        }
#pragma unroll
        for (int r = 0; r < 16; ++r) {
            s0v[r] = ex2(s0v[r] - m); ss += s0v[r];
            s1v[r] = ex2(s1v[r] - m); ss += s1v[r];
        }
        PV(s0v, s1v, t * 64, O0, O1);
        __syncthreads();
    }
    float sf = ss + __shfl_xor(ss, 32, 64);
    float inv = 1.0f / sf;
    SCALE_O(inv, O0, O1);

    // ---- fused depthwise conv33 as Toeplitz MFMA + output write ----
    if (isGene || orow0 < NTOK) {
        {
            const ushort* cr0 = vtb + ((size_t)(bh * DH) + ql) * VROW + orow0;  // +VPAD-16
            const ushort* cr1 = cr0 + (size_t)32 * VROW;
#pragma unroll
            for (int ki = 0; ki < 4; ++ki) {
                short8 v0 = *(const short8*)(cr0 + half * 8 + 16 * ki);
                short8 v1 = *(const short8*)(cr1 + half * 8 + 16 * ki);
                O0 = MFMA(tf[ki], v0, O0, 0, 0, 0);
                O1 = MFMA(tf[ki], v1, O1, 0, 0, 0);
            }
        }
#pragma unroll
        for (int r = 0; r < 16; ++r) {
            int qm = (r & 3) + 8 * (r >> 2) + 4 * half;
            int orow = orow0 + qm;
            if (isGene || orow < NTOK) {
                float* op = out + ((size_t)b * NTOK + orow) * DIM + h * DH + ql;
                op[0]  = O0[r];
                op[32] = O1[r];
            }
        }
    }
#undef STAGE_LOAD
#undef STAGE_WRITE
#undef QKT
#undef MASK_LAST
#undef TILEMAX
#undef PV
#undef SCALE_O
}

extern "C" void kernel_launch(void* const* d_in, const int* in_sizes, int n_in,
                              void* d_out, int out_size, void* d_ws, size_t ws_size,
                              hipStream_t stream)
{
    const float* x     = (const float*)d_in[0];
    const float* w_qkv = (const float*)d_in[1];
    const float* w_res = (const float*)d_in[2];
    float* out = (float*)d_out;

    const size_t qElems = (size_t)BATCH * HEADS * NTOK * DH;    // 5,386,240
    const size_t kElems = (size_t)BATCH * HEADS * KROWS * DH;   // 5,505,024
    const size_t vElems = (size_t)BATCH * HEADS * DH * VROW;    // 5,701,632
    const size_t wElems = (size_t)NQKV * DIM;                   // 786,432
    ushort* qbb = (ushort*)d_ws;
    ushort* kbb = qbb + qElems;
    ushort* vnb = kbb + kElems;          // row-major v staging
    ushort* vtb = vnb + qElems;
    ushort* wtb = vtb + vElems;          // [NQKV][DIM] bf16
    float*  vsm = (float*)(wtb + wElems);// [64][64] f32; total ws ~45.6 MB

    prep_zero<<<dim3(64), 256, 0, stream>>>(kbb, vtb);
    wtrans<<<dim3(NQKV / 64, DIM / 64), 256, 0, stream>>>(w_qkv, wtb);
    qkv_gemm<<<dim3(BATCH * 11, NQKV / 128), 256, 0, stream>>>(x, wtb, qbb, kbb, vnb);
    vtrans<<<dim3(BATCH * HEADS, NT), 256, 0, stream>>>(vnb, vtb);
    vsum_k<<<dim3(BATCH * HEADS), 256, 0, stream>>>(vnb, vsm);
    attn_fused<<<dim3(BATCH * HEADS, 11), 256, 0, stream>>>(qbb, kbb, vtb, w_res, vsm, out);
}